// Round 2
// baseline (1994.670 us; speedup 1.0000x reference)
//
#include <hip/hip_runtime.h>

// SimpleRNN: VOCAB=32000, EMBED=256, HIDDEN=512, N=256, L=512
// out = h_512 (256x512 f32), h_{t+1} = tanh(h W_hh^T + b_hh + b_xh + emb[X] W_xh^T)
//
// Plan:
//  preconv x2 : W_hh, W_xh fp32 -> f16 in MFMA fragment order (Whf, Wxf in d_ws)
//  phaseA     : embedding gather + Xproj GEMM (f16 MFMA), writes xpf[t][blk][w][nt][lane][r]
//               in the exact phase-B accumulator layout (biases folded in), f16, 128 MB in d_ws
//  phaseB     : persistent recurrence, 16 blocks x 512 threads, 16 batch rows per block,
//               W_hh f16 resident per-CU: k-tiles 0..11 in VGPRs (192/wave), 12..15 in LDS (128KB),
//               h (16x512 f16, XOR-swizzled) in LDS, 512 steps, no inter-block comms.

typedef _Float16 f16;
typedef f16 f16x8 __attribute__((ext_vector_type(8)));
typedef float f32x4 __attribute__((ext_vector_type(4)));
typedef unsigned short u16;

union U8 { uint4 u; f16x8 h; };
union U4 { uint2 u; f16 h[4]; };

// ---------------------------------------------------------------- preconv ---
// Frag layout: one frag = 64 lanes x 8 f16 (1KB). lane l supplies
// B[col = w*64 + nt*16 + (l&15)][k = kt*32 + (l>>4)*8 + j], j=0..7.
// mode 0 (W_xh, K=256): frag index f = (w*4+nt)*8 + kt   (per-wave contiguous)
// mode 1 (W_hh, K=512): frag index f = kt*32 + w*4 + nt  (k-tile major; tail kt 12..15
//                        is a contiguous 128KB chunk -> linear LDS copy in phaseB)
__global__ void preconv_kernel(const float* __restrict__ W, u16* __restrict__ dst,
                               int kstride, int mode) {
  int t = blockIdx.x * blockDim.x + threadIdx.x;
  int f = t >> 6, l = t & 63;
  int kt, w, nt;
  if (mode == 0) { kt = f & 7;  nt = (f >> 3) & 3; w = f >> 5; }
  else           { nt = f & 3;  w = (f >> 2) & 7;  kt = f >> 5; }
  int col = w * 64 + nt * 16 + (l & 15);
  int k   = kt * 32 + (l >> 4) * 8;
  const float* src = W + (size_t)col * kstride + k;
  float4 v0 = *(const float4*)src;
  float4 v1 = *(const float4*)(src + 4);
  U8 r;
  r.h = (f16x8){(f16)v0.x, (f16)v0.y, (f16)v0.z, (f16)v0.w,
                (f16)v1.x, (f16)v1.y, (f16)v1.z, (f16)v1.w};
  *(uint4*)(dst + (size_t)f * 512 + l * 8) = r.u;
}

// ----------------------------------------------------------------- phaseA ---
// Grid 1024 = 16 n-blocks (bn) x 64 l-blocks (bl, 8 timesteps each). Block: 512 thr, 8 waves.
// M-tile = 128 rows: row = j*16 + i  (j = l-offset 0..7 == staging wave, i = n-offset 0..15).
// Each MFMA m-tile (16 rows) = one timestep t = bl*8 + mt, 16 batch rows.
// Wave w computes cols [64w, 64w+64). K=256 entirely in LDS (64KB A-tile, XOR-swizzled).
__global__ __launch_bounds__(512, 2) void phaseA_kernel(
    const int* __restrict__ X, const float* __restrict__ emb,
    const u16* __restrict__ Wxf, const float* __restrict__ b_hh,
    const float* __restrict__ b_xh, u16* __restrict__ xpf) {
  __shared__ f16 A[128 * 256];  // 64 KB
  const int tid = threadIdx.x, w = tid >> 6, l = tid & 63;
  const int b = blockIdx.x, bn = b >> 6, bl = b & 63;
  const int lr = l & 15, lg = l >> 4;

  // B fragments for this wave's 64 cols: 32 frags = 128 VGPRs, contiguous in Wxf.
  f16x8 wx[4][8];
#pragma unroll
  for (int nt = 0; nt < 4; ++nt)
#pragma unroll
    for (int kt = 0; kt < 8; ++kt) {
      U8 u; u.u = *(const uint4*)(Wxf + (size_t)((w * 4 + nt) * 8 + kt) * 512 + l * 8);
      wx[nt][kt] = u.h;
    }
  float bias[4];
#pragma unroll
  for (int nt = 0; nt < 4; ++nt) {
    int c = w * 64 + nt * 16 + lr;
    bias[nt] = b_hh[c] + b_xh[c];   // fold BOTH biases into xproj
  }

  // Stage A-tile: wave w stages rows [16w, 16w+16) = all 16 n's at l-offset j=w.
  int xs[16];
  const int lseq = bl * 8 + w;
#pragma unroll
  for (int i = 0; i < 16; ++i) xs[i] = X[(bn * 16 + i) * 512 + lseq];
#pragma unroll
  for (int i = 0; i < 16; ++i) {
    float4 v = *(const float4*)(emb + (size_t)xs[i] * 256 + l * 4);
    U4 p; p.h[0] = (f16)v.x; p.h[1] = (f16)v.y; p.h[2] = (f16)v.z; p.h[3] = (f16)v.w;
    int row = w * 16 + i;
    *(uint2*)(&A[row * 256 + ((l * 4) ^ ((row & 7) << 3))]) = p.u;  // swizzled 8B write
  }
  __syncthreads();

#pragma unroll 1
  for (int mt = 0; mt < 8; ++mt) {
    f32x4 acc[4];
#pragma unroll
    for (int nt = 0; nt < 4; ++nt) acc[nt] = (f32x4){0.f, 0.f, 0.f, 0.f};
    const int row = mt * 16 + lr;
    const f16* Arow = &A[row * 256];
    const int sw = (lr & 7) << 3;
#pragma unroll
    for (int kt = 0; kt < 8; ++kt) {
      f16x8 a = *(const f16x8*)(Arow + ((kt * 32 + lg * 8) ^ sw));
#pragma unroll
      for (int nt = 0; nt < 4; ++nt)
        acc[nt] = __builtin_amdgcn_mfma_f32_16x16x32_f16(a, wx[nt][kt], acc[nt], 0, 0, 0);
    }
    const int t = bl * 8 + mt;
#pragma unroll
    for (int nt = 0; nt < 4; ++nt) {
      U4 p;
#pragma unroll
      for (int r = 0; r < 4; ++r) p.h[r] = (f16)(acc[nt][r] + bias[nt]);
      // xpf[t][bn][w][nt][lane][r], matches phase-B acc layout exactly
      *(uint2*)(xpf + ((((size_t)t * 16 + bn) * 8 + w) * 4 + nt) * 256 + l * 4) = p.u;
    }
  }
}

// ----------------------------------------------------------------- phaseB ---
// 16 blocks x 512 threads (8 waves, 2 waves/SIMD). Block bb owns batch rows [16bb,16bb+16).
// Wave w owns output cols [64w, 64w+64). h in LDS [16][512] f16, XOR-swizzled.
// W_hh: k-tiles 0..11 in registers (48 frags = 192 VGPR/wave), 12..15 in LDS (128 KB).
__global__ __launch_bounds__(512, 2) void phaseB_kernel(
    const u16* __restrict__ Whf, const u16* __restrict__ xpf,
    float* __restrict__ out) {
  extern __shared__ char smem[];
  f16* h_lds = (f16*)smem;               // 16 KB
  f16* w_lds = (f16*)(smem + 16 * 1024); // 128 KB
  const int tid = threadIdx.x, w = tid >> 6, l = tid & 63;
  const int bb = blockIdx.x;
  const int lr = l & 15, lg = l >> 4;

  // Register-resident W fragments (static indexing only -> stays in VGPRs)
  f16x8 wreg[12][4];
#pragma unroll
  for (int kt = 0; kt < 12; ++kt)
#pragma unroll
    for (int nt = 0; nt < 4; ++nt) {
      U8 u; u.u = *(const uint4*)(Whf + (size_t)(kt * 32 + w * 4 + nt) * 512 + l * 8);
      wreg[kt][nt] = u.h;
    }
  // LDS-resident tail: frags 384..511 are a contiguous 128 KB chunk -> linear copy
  {
    const uint4* src = (const uint4*)(Whf + (size_t)384 * 512);
    uint4* dst = (uint4*)w_lds;
#pragma unroll
    for (int i = 0; i < 16; ++i) dst[i * 512 + tid] = src[i * 512 + tid];
  }
  // h0 = 0
  {
    float* hz = (float*)h_lds;
#pragma unroll
    for (int i = 0; i < 8; ++i) hz[i * 512 + tid] = 0.f;
  }
  __syncthreads();

  const int rowbase = bb * 16;
  const int asw = (lr & 7) << 3;  // in-row half-index XOR mask for A reads (row = lr)

#pragma unroll 1
  for (int t = 0; t < 512; ++t) {
    // xp loads (independent of h) issue first, hide under the MFMA chain
    uint2 xp[4];
#pragma unroll
    for (int nt = 0; nt < 4; ++nt)
      xp[nt] = *(const uint2*)(xpf + ((((size_t)t * 16 + bb) * 8 + w) * 4 + nt) * 256 + l * 4);

    f32x4 acc[4];
#pragma unroll
    for (int nt = 0; nt < 4; ++nt) acc[nt] = (f32x4){0.f, 0.f, 0.f, 0.f};

#pragma unroll
    for (int kt = 0; kt < 16; ++kt) {
      f16x8 a = *(const f16x8*)(&h_lds[lr * 512 + ((kt * 32 + lg * 8) ^ asw)]);
#pragma unroll
      for (int nt = 0; nt < 4; ++nt) {
        f16x8 bfrag;
        if (kt < 12) {
          bfrag = wreg[kt][nt];
        } else {
          U8 u; u.u = *(const uint4*)((const u16*)w_lds +
                     (size_t)((kt - 12) * 32 + w * 4 + nt) * 512 + l * 8);
          bfrag = u.h;
        }
        acc[nt] = __builtin_amdgcn_mfma_f32_16x16x32_f16(a, bfrag, acc[nt], 0, 0, 0);
      }
    }
    __syncthreads();  // all h reads complete before overwrite

#pragma unroll
    for (int nt = 0; nt < 4; ++nt) {
      U4 px; px.u = xp[nt];
      const int col = w * 64 + nt * 16 + lr;
#pragma unroll
      for (int r = 0; r < 4; ++r) {
        const int row = lg * 4 + r;                 // verified C/D layout (m89)
        float z = acc[nt][r] + (float)px.h[r];
        // tanh(z) = 1 - 2/(e^{2z}+1); handles +-inf saturation without branches
        float th = 1.0f - 2.0f / (exp2f(z * 2.885390081777927f) + 1.0f);
        h_lds[row * 512 + (col ^ ((row & 7) << 3))] = (f16)th;
        if (t == 511) out[(size_t)(rowbase + row) * 512 + col] = th;
      }
    }
    __syncthreads();  // h_new visible before next step's reads
  }
}

// ------------------------------------------------------------------ launch --
extern "C" void kernel_launch(void* const* d_in, const int* in_sizes, int n_in,
                              void* d_out, int out_size, void* d_ws, size_t ws_size,
                              hipStream_t stream) {
  const int*   X    = (const int*)d_in[0];
  const float* emb  = (const float*)d_in[1];
  const float* W_hh = (const float*)d_in[2];
  const float* b_hh = (const float*)d_in[3];
  const float* W_xh = (const float*)d_in[4];
  const float* b_xh = (const float*)d_in[5];
  float* out = (float*)d_out;

  char* ws = (char*)d_ws;
  u16* Whf = (u16*)ws;                    // 512 KB
  u16* Wxf = (u16*)(ws + 524288);         // 256 KB
  u16* xpf = (u16*)(ws + 786432);         // 128 MB

  // Opt-in to >64KB dynamic LDS for phaseB (idempotent, not a stream op).
  hipFuncSetAttribute((const void*)phaseB_kernel,
                      hipFuncAttributeMaxDynamicSharedMemorySize, 147456);

  preconv_kernel<<<128, 256, 0, stream>>>(W_hh, Whf, 512, 1);
  preconv_kernel<<< 64, 256, 0, stream>>>(W_xh, Wxf, 256, 0);
  phaseA_kernel<<<1024, 512, 0, stream>>>(X, emb, Wxf, b_hh, b_xh, xpf);
  phaseB_kernel<<<16, 512, 147456, stream>>>(Whf, xpf, out);
}

// Round 5
// 1693.725 us; speedup vs baseline: 1.1777x; 1.1777x over previous
//
#include <hip/hip_runtime.h>

// SimpleRNN: VOCAB=32000, EMBED=256, HIDDEN=512, N=256, L=512
// out = h_512 (256x512 f32), h_{t+1} = tanh(h W_hh^T + b_hh + b_xh + emb[X] W_xh^T)
//
//  preconv x2 : W_hh, W_xh fp32 -> f16 in MFMA fragment order (Whf, Wxf) [= round-2 exact]
//  phaseA     : embedding gather + Xproj GEMM (f16 MFMA) -> xpf (biases folded) [= round-2 exact]
//  phaseB     : persistent recurrence, 16 blocks x 512 thr, 16 batch rows/block.
//               Double-buffered h (one barrier/step), xp prefetch one step ahead,
//               hoisted final store. xp t-stride FIXED: 131072 u16 (= 16*8*4*256),
//               rounds 3/4 wrongly used 32768 -> absmax 2.0.

typedef _Float16 f16;
typedef f16 f16x8 __attribute__((ext_vector_type(8)));
typedef float f32x4 __attribute__((ext_vector_type(4)));
typedef unsigned short u16;

union U8 { uint4 u; f16x8 h; };
union U4 { uint2 u; f16 h[4]; };

// ---------------------------------------------------------------- preconv ---
// One frag = 64 lanes x 8 f16 (1KB). lane l supplies
// B[col = w*64 + nt*16 + (l&15)][k = kt*32 + (l>>4)*8 + j], j=0..7.
// mode 0 (W_xh, K=256): f = (w*4+nt)*8 + kt
// mode 1 (W_hh, K=512): f = kt*32 + w*4 + nt            (round-2 layout, known-good)
__global__ void preconv_kernel(const float* __restrict__ W, u16* __restrict__ dst,
                               int kstride, int mode) {
  int t = blockIdx.x * blockDim.x + threadIdx.x;
  int f = t >> 6, l = t & 63;
  int kt, w, nt;
  if (mode == 0) { kt = f & 7;  nt = (f >> 3) & 3; w = f >> 5; }
  else           { nt = f & 3;  w = (f >> 2) & 7;  kt = f >> 5; }
  int col = w * 64 + nt * 16 + (l & 15);
  int k   = kt * 32 + (l >> 4) * 8;
  const float* src = W + (size_t)col * kstride + k;
  float4 v0 = *(const float4*)src;
  float4 v1 = *(const float4*)(src + 4);
  U8 r;
  r.h = (f16x8){(f16)v0.x, (f16)v0.y, (f16)v0.z, (f16)v0.w,
                (f16)v1.x, (f16)v1.y, (f16)v1.z, (f16)v1.w};
  *(uint4*)(dst + (size_t)f * 512 + l * 8) = r.u;
}

// ----------------------------------------------------------------- phaseA ---
// Grid 1024 = 16 n-blocks x 64 l-blocks (8 timesteps each). 512 thr, 8 waves.
__global__ __launch_bounds__(512, 2) void phaseA_kernel(
    const int* __restrict__ X, const float* __restrict__ emb,
    const u16* __restrict__ Wxf, const float* __restrict__ b_hh,
    const float* __restrict__ b_xh, u16* __restrict__ xpf) {
  __shared__ f16 A[128 * 256];  // 64 KB
  const int tid = threadIdx.x, w = tid >> 6, l = tid & 63;
  const int b = blockIdx.x, bn = b >> 6, bl = b & 63;
  const int lr = l & 15, lg = l >> 4;

  f16x8 wx[4][8];
#pragma unroll
  for (int nt = 0; nt < 4; ++nt)
#pragma unroll
    for (int kt = 0; kt < 8; ++kt) {
      U8 u; u.u = *(const uint4*)(Wxf + (size_t)((w * 4 + nt) * 8 + kt) * 512 + l * 8);
      wx[nt][kt] = u.h;
    }
  float bias[4];
#pragma unroll
  for (int nt = 0; nt < 4; ++nt) {
    int c = w * 64 + nt * 16 + lr;
    bias[nt] = b_hh[c] + b_xh[c];
  }

  int xs[16];
  const int lseq = bl * 8 + w;
#pragma unroll
  for (int i = 0; i < 16; ++i) xs[i] = X[(bn * 16 + i) * 512 + lseq];
#pragma unroll
  for (int i = 0; i < 16; ++i) {
    float4 v = *(const float4*)(emb + (size_t)xs[i] * 256 + l * 4);
    U4 p; p.h[0] = (f16)v.x; p.h[1] = (f16)v.y; p.h[2] = (f16)v.z; p.h[3] = (f16)v.w;
    int row = w * 16 + i;
    *(uint2*)(&A[row * 256 + ((l * 4) ^ ((row & 7) << 3))]) = p.u;
  }
  __syncthreads();

#pragma unroll 1
  for (int mt = 0; mt < 8; ++mt) {
    f32x4 acc[4];
#pragma unroll
    for (int nt = 0; nt < 4; ++nt) acc[nt] = (f32x4){0.f, 0.f, 0.f, 0.f};
    const int row = mt * 16 + lr;
    const f16* Arow = &A[row * 256];
    const int sw = (lr & 7) << 3;
#pragma unroll
    for (int kt = 0; kt < 8; ++kt) {
      f16x8 a = *(const f16x8*)(Arow + ((kt * 32 + lg * 8) ^ sw));
#pragma unroll
      for (int nt = 0; nt < 4; ++nt)
        acc[nt] = __builtin_amdgcn_mfma_f32_16x16x32_f16(a, wx[nt][kt], acc[nt], 0, 0, 0);
    }
    const int t = bl * 8 + mt;
#pragma unroll
    for (int nt = 0; nt < 4; ++nt) {
      U4 p;
#pragma unroll
      for (int r = 0; r < 4; ++r) p.h[r] = (f16)(acc[nt][r] + bias[nt]);
      *(uint2*)(xpf + ((((size_t)t * 16 + bn) * 8 + w) * 4 + nt) * 256 + l * 4) = p.u;
    }
  }
}

// ----------------------------------------------------------------- phaseB ---
// 16 blocks x 512 thr (8 waves, 2/SIMD). Block bb: batch rows [16bb,16bb+16).
// Wave w: cols [64w,64w+64). h double-buffered in LDS, XOR-swizzled.
// W_hh: kt 0..11 in regs, kt 12..15 in LDS (both round-2 layout/indexing).

__device__ __forceinline__ void rnn_step(
    const f16* __restrict__ hr, f16* __restrict__ hw,
    const uint2* __restrict__ xp, const f16x8 (*__restrict__ wreg)[4],
    const u16* __restrict__ wtail, int w, int lr, int lg, int asw) {
  f32x4 acc[4];
#pragma unroll
  for (int nt = 0; nt < 4; ++nt) acc[nt] = (f32x4){0.f, 0.f, 0.f, 0.f};

#pragma unroll
  for (int kt = 0; kt < 16; ++kt) {
    f16x8 a = *(const f16x8*)(hr + lr * 512 + ((kt * 32 + lg * 8) ^ asw));
#pragma unroll
    for (int nt = 0; nt < 4; ++nt) {
      f16x8 bfrag;
      if (kt < 12) {
        bfrag = wreg[kt][nt];
      } else {
        U8 u; u.u = *(const uint4*)(wtail + (size_t)((kt - 12) * 32 + nt) * 512);
        bfrag = u.h;
      }
      acc[nt] = __builtin_amdgcn_mfma_f32_16x16x32_f16(a, bfrag, acc[nt], 0, 0, 0);
    }
  }

#pragma unroll
  for (int nt = 0; nt < 4; ++nt) {
    U4 px; px.u = xp[nt];
    const int col = w * 64 + nt * 16 + lr;
#pragma unroll
    for (int r = 0; r < 4; ++r) {
      const int row = lg * 4 + r;                 // C/D layout (m89)
      float z = acc[nt][r] + (float)px.h[r];
      // tanh(z) = 1 - 2/(2^(2z/ln2)+1); hw exp2 + rcp (rel err ~1e-6 << f16 state quant)
      float e = exp2f(z * 2.885390081777927f);
      float th = 1.0f - 2.0f * __builtin_amdgcn_rcpf(e + 1.0f);
      hw[row * 512 + (col ^ ((row & 7) << 3))] = (f16)th;
    }
  }
  __syncthreads();   // hw visible; all hr reads were before this barrier
}

__global__ __launch_bounds__(512, 2) void phaseB_kernel(
    const u16* __restrict__ Whf, const u16* __restrict__ xpf,
    float* __restrict__ out) {
  extern __shared__ char smem[];
  f16* h0 = (f16*)smem;                    // 16 KB, even steps read this
  f16* h1 = (f16*)(smem + 16 * 1024);      // 16 KB
  f16* w_lds = (f16*)(smem + 32 * 1024);   // 128 KB (frags 384..511 linear)
  const int tid = threadIdx.x, w = tid >> 6, l = tid & 63;
  const int bb = blockIdx.x;
  const int lr = l & 15, lg = l >> 4;

  f16x8 wreg[12][4];
#pragma unroll
  for (int kt = 0; kt < 12; ++kt)
#pragma unroll
    for (int nt = 0; nt < 4; ++nt) {
      U8 u; u.u = *(const uint4*)(Whf + (size_t)(kt * 32 + w * 4 + nt) * 512 + l * 8);
      wreg[kt][nt] = u.h;
    }
  {
    const uint4* src = (const uint4*)(Whf + (size_t)384 * 512);
    uint4* dst = (uint4*)w_lds;
#pragma unroll
    for (int i = 0; i < 16; ++i) dst[i * 512 + tid] = src[i * 512 + tid];
  }
  { // h0 = 0 (h1 is written before first read)
    float* hz = (float*)h0;
#pragma unroll
    for (int i = 0; i < 8; ++i) hz[i * 512 + tid] = 0.f;
  }
  __syncthreads();

  // per-lane invariants. xpf[t][bb][w][nt][l*4+r]: t-stride = 16*8*4*256 = 131072 u16.
  const u16* wtail  = (const u16*)w_lds + (size_t)(w * 4) * 512 + l * 8;
  const u16* xpbase = xpf + (size_t)bb * 8192 + w * 1024 + l * 4;
  const int asw = (lr & 7) << 3;

  uint2 xpA[4], xpB[4];
#pragma unroll
  for (int nt = 0; nt < 4; ++nt) xpA[nt] = *(const uint2*)(xpbase + nt * 256);

#pragma unroll 1
  for (int tt = 0; tt < 256; ++tt) {
    const int t = tt * 2;
    { // prefetch xp for step t+1 (hides under step t's MFMA section)
      const u16* p = xpbase + (size_t)(t + 1) * 131072;
#pragma unroll
      for (int nt = 0; nt < 4; ++nt) xpB[nt] = *(const uint2*)(p + nt * 256);
    }
    rnn_step(h0, h1, xpA, wreg, wtail, w, lr, lg, asw);   // step t: read h0, write h1
    { // prefetch xp for step t+2 (clamped; final value unused but in-bounds)
      const int tn = (t + 2 < 512) ? (t + 2) : 511;
      const u16* p = xpbase + (size_t)tn * 131072;
#pragma unroll
      for (int nt = 0; nt < 4; ++nt) xpA[nt] = *(const uint2*)(p + nt * 256);
    }
    rnn_step(h1, h0, xpB, wreg, wtail, w, lr, lg, asw);   // step t+1: read h1, write h0
  }

  // final h lives in h0 (step 511 wrote it; rnn_step ended with a barrier)
#pragma unroll
  for (int i = 0; i < 16; ++i) {
    f16 v = h0[i * 512 + (tid ^ ((i & 7) << 3))];
    out[(size_t)(bb * 16 + i) * 512 + tid] = (float)v;
  }
}

// ------------------------------------------------------------------ launch --
extern "C" void kernel_launch(void* const* d_in, const int* in_sizes, int n_in,
                              void* d_out, int out_size, void* d_ws, size_t ws_size,
                              hipStream_t stream) {
  const int*   X    = (const int*)d_in[0];
  const float* emb  = (const float*)d_in[1];
  const float* W_hh = (const float*)d_in[2];
  const float* b_hh = (const float*)d_in[3];
  const float* W_xh = (const float*)d_in[4];
  const float* b_xh = (const float*)d_in[5];
  float* out = (float*)d_out;

  char* ws = (char*)d_ws;
  u16* Whf = (u16*)ws;                    // 512 KB
  u16* Wxf = (u16*)(ws + 524288);         // 256 KB
  u16* xpf = (u16*)(ws + 786432);         // 128 MB

  hipFuncSetAttribute((const void*)phaseB_kernel,
                      hipFuncAttributeMaxDynamicSharedMemorySize, 163840);

  preconv_kernel<<<128, 256, 0, stream>>>(W_hh, Whf, 512, 1);
  preconv_kernel<<< 64, 256, 0, stream>>>(W_xh, Wxf, 256, 0);
  phaseA_kernel<<<1024, 512, 0, stream>>>(X, emb, Wxf, b_hh, b_xh, xpf);
  phaseB_kernel<<<16, 512, 163840, stream>>>(Whf, xpf, out);
}

// Round 6
// 1103.957 us; speedup vs baseline: 1.8068x; 1.5342x over previous
//
#include <hip/hip_runtime.h>

// SimpleRNN: VOCAB=32000, EMBED=256, HIDDEN=512, N=256, L=512
// out = h_512 (256x512 f32), h_{t+1} = tanh(h W_hh^T + b_hh + b_xh + emb[X] W_xh^T)
//
// Round-6 structure (transposed MFMA): compute Z = W·h^T so each lane's 4 acc
// values are 4 CONSECUTIVE out-cols of ONE batch row -> b64 h-writes, uint2 xp.
//  preconv : W -> f16 A/B-fragments (lane map row/col=l&15, k=(l>>4)*8+j; HW-verified r2).
//            W_hh tail frags reordered per-wave-contiguous: f = 384 + w*16 + mt*4 + (kt-12).
//  phaseA  : A=W_xh (regs), B=Xe (LDS); writes xpf[t][col>>2][n][4] f16 (biases folded).
//  phaseB  : 16 blocks x 512 thr, waves_per_eu(2,2) -> 256-VGPR budget so
//            W kt 0..11 (192 VGPR) stays RESIDENT; kt 12..15 from LDS (128 KB).
//            h (16x512 f16, XOR-swizzled) double-buffered, 1 barrier/step.

typedef _Float16 f16;
typedef f16 f16x8 __attribute__((ext_vector_type(8)));
typedef float f32x4 __attribute__((ext_vector_type(4)));
typedef unsigned short u16;

union U8 { uint4 u; f16x8 h; };
union U4 { uint2 u; f16 h[4]; };

// ---------------------------------------------------------------- preconv ---
// One frag = 64 lanes x 8 f16 (1KB). lane l supplies W[idx16 = g*16 + (l&15)][k = kt*32 + (l>>4)*8 + j].
// mode 0 (W_xh, K=256): f = (w*4+mt)*8 + kt
// mode 1 (W_hh, K=512): kt<12 : f = kt*32 + w*4 + mt
//                       kt>=12: f = 384 + w*16 + mt*4 + (kt-12)   (per-wave 16KB chunks)
__global__ void preconv_kernel(const float* __restrict__ W, u16* __restrict__ dst,
                               int kstride, int mode) {
  int t = blockIdx.x * blockDim.x + threadIdx.x;
  int f = t >> 6, l = t & 63;
  int kt, w, nt;
  if (mode == 0)    { kt = f & 7;  nt = (f >> 3) & 3; w = f >> 5; }
  else if (f < 384) { nt = f & 3;  w = (f >> 2) & 7;  kt = f >> 5; }
  else { int g = f - 384; kt = 12 + (g & 3); nt = (g >> 2) & 3; w = g >> 4; }
  int col = w * 64 + nt * 16 + (l & 15);
  int k   = kt * 32 + (l >> 4) * 8;
  const float* src = W + (size_t)col * kstride + k;
  float4 v0 = *(const float4*)src;
  float4 v1 = *(const float4*)(src + 4);
  U8 r;
  r.h = (f16x8){(f16)v0.x, (f16)v0.y, (f16)v0.z, (f16)v0.w,
                (f16)v1.x, (f16)v1.y, (f16)v1.z, (f16)v1.w};
  *(uint4*)(dst + (size_t)f * 512 + l * 8) = r.u;
}

// ----------------------------------------------------------------- phaseA ---
// Grid 1024 = 16 n-blocks x 64 l-blocks (8 timesteps each). 512 thr, 8 waves.
// A = W_xh (regs, m = out_cols: wave w owns [64w,64w+64)), B = Xe staged in LDS.
// D[row=out-col-in-tile=lg*4+r][col=batchseq-in-tile=lr] (HW-verified C/D map).
__global__ __launch_bounds__(512, 2) void phaseA_kernel(
    const int* __restrict__ X, const float* __restrict__ emb,
    const u16* __restrict__ Wxf, const float* __restrict__ b_hh,
    const float* __restrict__ b_xh, u16* __restrict__ xpf) {
  __shared__ f16 A[128 * 256];  // 64 KB, row = local batchseq (j*16+i), k = emb dim
  const int tid = threadIdx.x, w = tid >> 6, l = tid & 63;
  const int b = blockIdx.x, bn = b >> 6, bl = b & 63;
  const int lr = l & 15, lg = l >> 4;

  f16x8 wx[4][8];  // [mt][kt]
#pragma unroll
  for (int mt = 0; mt < 4; ++mt)
#pragma unroll
    for (int kt = 0; kt < 8; ++kt) {
      U8 u; u.u = *(const uint4*)(Wxf + (size_t)((w * 4 + mt) * 8 + kt) * 512 + l * 8);
      wx[mt][kt] = u.h;
    }
  float bias[4][4];
#pragma unroll
  for (int mt = 0; mt < 4; ++mt)
#pragma unroll
    for (int r = 0; r < 4; ++r) {
      int c = w * 64 + mt * 16 + lg * 4 + r;
      bias[mt][r] = b_hh[c] + b_xh[c];
    }

  // Stage Xe rows: wave w stages rows [16w,16w+16) = all 16 batches at l-offset j=w.
  int xs[16];
  const int lseq = bl * 8 + w;
#pragma unroll
  for (int i = 0; i < 16; ++i) xs[i] = X[(bn * 16 + i) * 512 + lseq];
#pragma unroll
  for (int i = 0; i < 16; ++i) {
    float4 v = *(const float4*)(emb + (size_t)xs[i] * 256 + l * 4);
    U4 p; p.h[0] = (f16)v.x; p.h[1] = (f16)v.y; p.h[2] = (f16)v.z; p.h[3] = (f16)v.w;
    int row = w * 16 + i;
    *(uint2*)(&A[row * 256 + ((l * 4) ^ ((row & 7) << 3))]) = p.u;
  }
  __syncthreads();

#pragma unroll 1
  for (int nt = 0; nt < 8; ++nt) {   // B-tile = timestep offset j = nt
    f32x4 acc[4];
#pragma unroll
    for (int mt = 0; mt < 4; ++mt) acc[mt] = (f32x4){0.f, 0.f, 0.f, 0.f};
    const f16* Brow = &A[(nt * 16 + lr) * 256];
    const int sw = (lr & 7) << 3;
#pragma unroll
    for (int kt = 0; kt < 8; ++kt) {
      f16x8 bfr = *(const f16x8*)(Brow + ((kt * 32 + lg * 8) ^ sw));
#pragma unroll
      for (int mt = 0; mt < 4; ++mt)
        acc[mt] = __builtin_amdgcn_mfma_f32_16x16x32_f16(wx[mt][kt], bfr, acc[mt], 0, 0, 0);
    }
    const int t = bl * 8 + nt;
    // xpf[t][cq=col>>2][n=256][4]: flat u16 = t*131072 + cq*1024 + n*4
#pragma unroll
    for (int mt = 0; mt < 4; ++mt) {
      U4 p;
#pragma unroll
      for (int r = 0; r < 4; ++r) p.h[r] = (f16)(acc[mt][r] + bias[mt][r]);
      *(uint2*)(xpf + (size_t)t * 131072 + (w * 16 + mt * 4 + lg) * 1024
                    + (bn * 16 + lr) * 4) = p.u;
    }
  }
}

// ----------------------------------------------------------------- phaseB ---
// 16 blocks x 512 thr (8 waves, PINNED 2 waves/SIMD -> 256 VGPR budget).
// Block bb: batch rows [16bb,16bb+16). Wave w: out cols [64w,64w+64).
// h storage rule: h[row=batch][col] at u16 idx row*512 + (col ^ ((row&7)<<3)).
__global__ __launch_bounds__(512)
__attribute__((amdgpu_waves_per_eu(2, 2)))
void phaseB_kernel(const u16* __restrict__ Whf, const u16* __restrict__ xpf,
                   float* __restrict__ out) {
  extern __shared__ char smem[];
  f16* h0 = (f16*)smem;                    // 16 KB (even steps read)
  f16* h1 = (f16*)(smem + 16 * 1024);      // 16 KB
  u16* wl = (u16*)(smem + 32 * 1024);      // 128 KB W tail (frags 384..511 linear)
  const int tid = threadIdx.x, w = tid >> 6, l = tid & 63;
  const int bb = blockIdx.x;
  const int lr = l & 15, lg = l >> 4;

  // W head resident: wa[kt][mt], frag f = kt*32 + w*4 + mt  (192 VGPR)
  f16x8 wa[12][4];
#pragma unroll
  for (int kt = 0; kt < 12; ++kt)
#pragma unroll
    for (int mt = 0; mt < 4; ++mt) {
      U8 u; u.u = *(const uint4*)(Whf + (size_t)(kt * 32 + w * 4 + mt) * 512 + l * 8);
      wa[kt][mt] = u.h;
    }
  { // tail copy (contiguous 128 KB)
    const uint4* src = (const uint4*)(Whf + (size_t)384 * 512);
    uint4* dst = (uint4*)wl;
#pragma unroll
    for (int i = 0; i < 16; ++i) dst[i * 512 + tid] = src[i * 512 + tid];
  }
  { // h0 = 0
    float* hz = (float*)h0;
#pragma unroll
    for (int i = 0; i < 8; ++i) hz[i * 512 + tid] = 0.f;
  }
  __syncthreads();

  // per-lane invariants
  const u16* wt  = wl + w * 8192 + l * 8;                 // + (mt*4 + kt-12)*512
  const u16* xpb = xpf + (w * 16 + lg) * 1024 + (bb * 16 + lr) * 4;  // + t*131072 + mt*4096
  const int asw = (lr & 7) << 3;

#define RNN_STEP(HR, HW, XP)                                                     \
  do {                                                                           \
    f32x4 acc[4];                                                                \
    _Pragma("unroll")                                                            \
    for (int mt = 0; mt < 4; ++mt) acc[mt] = (f32x4){0.f, 0.f, 0.f, 0.f};        \
    _Pragma("unroll")                                                            \
    for (int kt = 0; kt < 12; ++kt) {                                            \
      f16x8 hb = *(const f16x8*)((HR) + lr * 512 + ((kt * 32 + lg * 8) ^ asw));  \
      _Pragma("unroll")                                                          \
      for (int mt = 0; mt < 4; ++mt)                                             \
        acc[mt] = __builtin_amdgcn_mfma_f32_16x16x32_f16(wa[kt][mt], hb, acc[mt], 0, 0, 0); \
    }                                                                            \
    _Pragma("unroll")                                                            \
    for (int kt = 12; kt < 16; ++kt) {                                           \
      f16x8 hb = *(const f16x8*)((HR) + lr * 512 + ((kt * 32 + lg * 8) ^ asw));  \
      _Pragma("unroll")                                                          \
      for (int mt = 0; mt < 4; ++mt) {                                           \
        U8 u; u.u = *(const uint4*)(wt + (mt * 4 + (kt - 12)) * 512);            \
        acc[mt] = __builtin_amdgcn_mfma_f32_16x16x32_f16(u.h, hb, acc[mt], 0, 0, 0); \
      }                                                                          \
    }                                                                            \
    _Pragma("unroll")                                                            \
    for (int mt = 0; mt < 4; ++mt) {                                             \
      U4 px; px.u = (XP)[mt];                                                    \
      U4 o;                                                                      \
      _Pragma("unroll")                                                          \
      for (int r = 0; r < 4; ++r) {                                              \
        float z = acc[mt][r] + (float)px.h[r];                                   \
        float e = exp2f(z * 2.885390081777927f);                                 \
        o.h[r] = (f16)(1.0f - 2.0f * __builtin_amdgcn_rcpf(e + 1.0f));           \
      }                                                                          \
      *(uint2*)((HW) + lr * 512 + ((w * 64 + mt * 16 + lg * 4) ^ asw)) = o.u;    \
    }                                                                            \
    __syncthreads();                                                             \
  } while (0)

  uint2 xpA[4], xpB[4];
#pragma unroll
  for (int mt = 0; mt < 4; ++mt) xpA[mt] = *(const uint2*)(xpb + mt * 4096);

#pragma unroll 1
  for (int tt = 0; tt < 256; ++tt) {
    const int t = tt * 2;
    { // prefetch xp for step t+1
      const u16* p = xpb + (size_t)(t + 1) * 131072;
#pragma unroll
      for (int mt = 0; mt < 4; ++mt) xpB[mt] = *(const uint2*)(p + mt * 4096);
    }
    RNN_STEP(h0, h1, xpA);   // step t: read h0, write h1
    { // prefetch xp for step t+2 (clamped, in-bounds)
      const int tn = (t + 2 < 512) ? (t + 2) : 511;
      const u16* p = xpb + (size_t)tn * 131072;
#pragma unroll
      for (int mt = 0; mt < 4; ++mt) xpA[mt] = *(const uint2*)(p + mt * 4096);
    }
    RNN_STEP(h1, h0, xpB);   // step t+1: read h1, write h0
  }
#undef RNN_STEP

  // final h in h0; storage rule row=i, col=tid
#pragma unroll
  for (int i = 0; i < 16; ++i) {
    f16 v = h0[i * 512 + (tid ^ ((i & 7) << 3))];
    out[(size_t)(bb * 16 + i) * 512 + tid] = (float)v;
  }
}

// ------------------------------------------------------------------ launch --
extern "C" void kernel_launch(void* const* d_in, const int* in_sizes, int n_in,
                              void* d_out, int out_size, void* d_ws, size_t ws_size,
                              hipStream_t stream) {
  const int*   X    = (const int*)d_in[0];
  const float* emb  = (const float*)d_in[1];
  const float* W_hh = (const float*)d_in[2];
  const float* b_hh = (const float*)d_in[3];
  const float* W_xh = (const float*)d_in[4];
  const float* b_xh = (const float*)d_in[5];
  float* out = (float*)d_out;

  char* ws = (char*)d_ws;
  u16* Whf = (u16*)ws;                    // 512 KB
  u16* Wxf = (u16*)(ws + 524288);         // 256 KB
  u16* xpf = (u16*)(ws + 786432);         // 128 MB

  hipFuncSetAttribute((const void*)phaseB_kernel,
                      hipFuncAttributeMaxDynamicSharedMemorySize, 163840);

  preconv_kernel<<<128, 256, 0, stream>>>(W_hh, Whf, 512, 1);
  preconv_kernel<<< 64, 256, 0, stream>>>(W_xh, Wxf, 256, 0);
  phaseA_kernel<<<1024, 512, 0, stream>>>(X, emb, Wxf, b_hh, b_xh, xpf);
  phaseB_kernel<<<16, 512, 163840, stream>>>(Whf, xpf, out);
}